// Round 5
// baseline (430.653 us; speedup 1.0000x reference)
//
#include <hip/hip_runtime.h>
#include <math.h>

#define NN 100000
#define DIN 256
#define DH 128
#define NCHUNK 98          // ceil(100000/1024)
#define GEMM_NB 1563       // ceil(NN/64)
#define GEMM_NB1 512       // gemm blocks overlapped with hist
#define GEMM_NB2 (GEMM_NB - GEMM_NB1)

using short8  = __attribute__((ext_vector_type(8))) short;
using float4v = __attribute__((ext_vector_type(4))) float;

static __device__ __forceinline__ unsigned short f2bf(float f) {
    unsigned u = __float_as_uint(f);
    unsigned r = u + 0x7fffu + ((u >> 16) & 1u);   // round-to-nearest-even
    return (unsigned short)(r >> 16);
}
static __device__ __forceinline__ float bf_lo(unsigned u) { return __uint_as_float(u << 16); }
static __device__ __forceinline__ float bf_hi(unsigned u) { return __uint_as_float(u & 0xffff0000u); }

// ---------------- GEMM body (MFMA bf16): hs_bf16 = x @ W1 (UNSCALED) ----------------
static __device__ __forceinline__ void gemm_body(int gb, const float* __restrict__ x,
                                                 const float* __restrict__ W1,
                                                 unsigned short* __restrict__ hs) {
    __shared__ unsigned short aL[64 * 32 * 8];   // 32 KB, 16B-chunk XOR swizzle
    const int tid  = threadIdx.x;
    const int wave = tid >> 6;
    const int lane = tid & 63;
    const int quad = lane >> 4;
    const int m16  = lane & 15;
    const int row0 = gb * 64;
    const int n0   = wave * 32;

    short8 bfr[2][8];
#pragma unroll
    for (int ks = 0; ks < 8; ++ks) {
#pragma unroll
        for (int nt = 0; nt < 2; ++nt) {
            short8 v;
            int n = n0 + nt * 16 + m16;
#pragma unroll
            for (int j = 0; j < 8; ++j) {
                float w = W1[(ks * 32 + quad * 8 + j) * DH + n];
                v[j] = (short)f2bf(w);
            }
            bfr[nt][ks] = v;
        }
    }

#pragma unroll
    for (int it = 0; it < 8; ++it) {
        int id  = it * 256 + tid;
        int row = id >> 5;
        int kb  = id & 31;
        int gr  = row0 + row;
        float4 f0, f1;
        if (gr < NN) {
            const float* xp = &x[(long long)gr * DIN + kb * 8];
            f0 = *(const float4*)xp;
            f1 = *(const float4*)(xp + 4);
        } else {
            f0 = make_float4(0.f, 0.f, 0.f, 0.f);
            f1 = f0;
        }
        short8 v;
        v[0] = (short)f2bf(f0.x); v[1] = (short)f2bf(f0.y);
        v[2] = (short)f2bf(f0.z); v[3] = (short)f2bf(f0.w);
        v[4] = (short)f2bf(f1.x); v[5] = (short)f2bf(f1.y);
        v[6] = (short)f2bf(f1.z); v[7] = (short)f2bf(f1.w);
        int chunk = row * 32 + (kb ^ (row & 31));
        *(short8*)&aL[chunk * 8] = v;
    }
    __syncthreads();

    float4v acc[4][2];
#pragma unroll
    for (int mt = 0; mt < 4; ++mt)
#pragma unroll
        for (int nt = 0; nt < 2; ++nt)
            acc[mt][nt] = (float4v)(0.0f);

#pragma unroll
    for (int mt = 0; mt < 4; ++mt) {
        int row = mt * 16 + m16;
#pragma unroll
        for (int ks = 0; ks < 8; ++ks) {
            int kb = ks * 4 + quad;
            int chunk = row * 32 + (kb ^ (row & 31));
            short8 a = *(const short8*)&aL[chunk * 8];
            acc[mt][0] = __builtin_amdgcn_mfma_f32_16x16x32_bf16(a, bfr[0][ks], acc[mt][0], 0, 0, 0);
            acc[mt][1] = __builtin_amdgcn_mfma_f32_16x16x32_bf16(a, bfr[1][ks], acc[mt][1], 0, 0, 0);
        }
    }

#pragma unroll
    for (int mt = 0; mt < 4; ++mt) {
#pragma unroll
        for (int r = 0; r < 4; ++r) {
            int row = row0 + mt * 16 + quad * 4 + r;
            if (row < NN) {
#pragma unroll
                for (int nt = 0; nt < 2; ++nt)
                    hs[(long long)row * DH + n0 + nt * 16 + m16] = f2bf(acc[mt][nt][r]);
            }
        }
    }
}

// ---------------- K1: gemm part-A  ||  dst histogram (4 edges/thread) ----------------
__global__ __launch_bounds__(256) void k_gemm_hist(const float* __restrict__ x,
                                                   const float* __restrict__ W1,
                                                   unsigned short* __restrict__ hs,
                                                   const int* __restrict__ dst, int E,
                                                   int* __restrict__ cnt) {
    if ((int)blockIdx.x < GEMM_NB1) { gemm_body(blockIdx.x, x, W1, hs); return; }
    int e0 = (((int)blockIdx.x - GEMM_NB1) * 256 + (int)threadIdx.x) * 4;
    if (e0 + 3 < E) {
        int4 d4 = *(const int4*)&dst[e0];
        atomicAdd(&cnt[d4.x], 1);
        atomicAdd(&cnt[d4.y], 1);
        atomicAdd(&cnt[d4.z], 1);
        atomicAdd(&cnt[d4.w], 1);
    } else {
        for (int e = e0; e < E; ++e) atomicAdd(&cnt[dst[e]], 1);
    }
}

// ---------------- scan level 1 + dinv fused ----------------
__global__ __launch_bounds__(256) void k_scan1d(const int* __restrict__ cnt,
                                                int* __restrict__ excl,
                                                int* __restrict__ chunkSums,
                                                float* __restrict__ dinv) {
    __shared__ int tmp[256];
    int t = threadIdx.x;
    int i0 = blockIdx.x * 1024 + t * 4;
    int v0 = (i0 + 0 < NN) ? cnt[i0 + 0] : 0;
    int v1 = (i0 + 1 < NN) ? cnt[i0 + 1] : 0;
    int v2 = (i0 + 2 < NN) ? cnt[i0 + 2] : 0;
    int v3 = (i0 + 3 < NN) ? cnt[i0 + 3] : 0;
    int s0 = v0, s1 = s0 + v1, s2 = s1 + v2, s3 = s2 + v3;
    tmp[t] = s3;
    __syncthreads();
    for (int off = 1; off < 256; off <<= 1) {
        int val = (t >= off) ? tmp[t - off] : 0;
        __syncthreads();
        tmp[t] += val;
        __syncthreads();
    }
    int prev = (t > 0) ? tmp[t - 1] : 0;
    if (i0 + 0 < NN) { excl[i0 + 0] = prev;      dinv[i0 + 0] = rsqrtf(1.0f + (float)v0); }
    if (i0 + 1 < NN) { excl[i0 + 1] = prev + s0; dinv[i0 + 1] = rsqrtf(1.0f + (float)v1); }
    if (i0 + 2 < NN) { excl[i0 + 2] = prev + s1; dinv[i0 + 2] = rsqrtf(1.0f + (float)v2); }
    if (i0 + 3 < NN) { excl[i0 + 3] = prev + s2; dinv[i0 + 3] = rsqrtf(1.0f + (float)v3); }
    if (t == 255) chunkSums[blockIdx.x] = tmp[255];
}

__global__ __launch_bounds__(128) void k_scan2(const int* __restrict__ chunkSums,
                                               int* __restrict__ chunkOff) {
    __shared__ int tmp[128];
    int t = threadIdx.x;
    tmp[t] = (t < NCHUNK) ? chunkSums[t] : 0;
    __syncthreads();
    for (int off = 1; off < 128; off <<= 1) {
        int val = (t >= off) ? tmp[t - off] : 0;
        __syncthreads();
        tmp[t] += val;
        __syncthreads();
    }
    chunkOff[t] = (t > 0) ? tmp[t - 1] : 0;
}

// ---------------- K4: gemm part-B  ||  CSR fill (4 edges/thread) ----------------
__global__ __launch_bounds__(256) void k_gemm_fill(const float* __restrict__ x,
                                                   const float* __restrict__ W1,
                                                   unsigned short* __restrict__ hs,
                                                   const int* __restrict__ src,
                                                   const int* __restrict__ dst, int E,
                                                   const int* __restrict__ excl,
                                                   const int* __restrict__ chunkOff,
                                                   int* __restrict__ cnt2,
                                                   int* __restrict__ eidx) {
    if ((int)blockIdx.x < GEMM_NB2) { gemm_body(GEMM_NB1 + blockIdx.x, x, W1, hs); return; }
    int e0 = (((int)blockIdx.x - GEMM_NB2) * 256 + (int)threadIdx.x) * 4;
    if (e0 + 3 < E) {
        int4 d4 = *(const int4*)&dst[e0];
        int4 s4 = *(const int4*)&src[e0];
        int b0 = excl[d4.x] + chunkOff[d4.x >> 10];
        int b1 = excl[d4.y] + chunkOff[d4.y >> 10];
        int b2 = excl[d4.z] + chunkOff[d4.z >> 10];
        int b3 = excl[d4.w] + chunkOff[d4.w >> 10];
        int o0 = atomicAdd(&cnt2[d4.x], 1);
        int o1 = atomicAdd(&cnt2[d4.y], 1);
        int o2 = atomicAdd(&cnt2[d4.z], 1);
        int o3 = atomicAdd(&cnt2[d4.w], 1);
        eidx[b0 + o0] = s4.x;
        eidx[b1 + o1] = s4.y;
        eidx[b2 + o2] = s4.z;
        eidx[b3 + o3] = s4.w;
    } else {
        for (int e = e0; e < E; ++e) {
            int d = dst[e];
            int slot = excl[d] + chunkOff[d >> 10] + atomicAdd(&cnt2[d], 1);
            eidx[slot] = src[e];
        }
    }
}

// ---------------- fused layer-1 aggregation + layer-2 linear: one wave per node ----------------
__global__ __launch_bounds__(256) void k_agg1l2(const int* __restrict__ eidx,
                                                const int* __restrict__ excl,
                                                const int* __restrict__ chunkOff,
                                                const int* __restrict__ cnt,
                                                const unsigned* __restrict__ hs2,  // 64 uints/row
                                                const float* __restrict__ dinv,
                                                const float* __restrict__ b1,
                                                const float* __restrict__ W2,
                                                float* __restrict__ zs) {
    int w = (blockIdx.x * 256 + threadIdx.x) >> 6;
    if (w >= NN) return;
    int lane = threadIdx.x & 63;
    int offs = excl[w] + chunkOff[w >> 10];
    int c = cnt[w];

    float dw = dinv[w];
    unsigned u = hs2[(long long)w * 64 + lane];   // self-loop
    float ax = dw * bf_lo(u);
    float ay = dw * bf_hi(u);

    int j = 0;
    for (; j + 7 < c; j += 8) {
        int s[8]; float es[8]; unsigned uu[8];
#pragma unroll
        for (int q = 0; q < 8; ++q) s[q] = eidx[offs + j + q];
#pragma unroll
        for (int q = 0; q < 8; ++q) es[q] = dinv[s[q]];
#pragma unroll
        for (int q = 0; q < 8; ++q) uu[q] = hs2[(long long)s[q] * 64 + lane];
#pragma unroll
        for (int q = 0; q < 8; ++q) {
            ax = fmaf(es[q], bf_lo(uu[q]), ax);
            ay = fmaf(es[q], bf_hi(uu[q]), ay);
        }
    }
    for (; j + 1 < c; j += 2) {
        int s0 = eidx[offs + j], s1 = eidx[offs + j + 1];
        float e0 = dinv[s0], e1 = dinv[s1];
        unsigned u0 = hs2[(long long)s0 * 64 + lane];
        unsigned u1 = hs2[(long long)s1 * 64 + lane];
        ax = fmaf(e0, bf_lo(u0), ax); ay = fmaf(e0, bf_hi(u0), ay);
        ax = fmaf(e1, bf_lo(u1), ax); ay = fmaf(e1, bf_hi(u1), ay);
    }
    if (j < c) {
        int s0 = eidx[offs + j];
        float e0 = dinv[s0];
        unsigned u0 = hs2[(long long)s0 * 64 + lane];
        ax = fmaf(e0, bf_lo(u0), ax); ay = fmaf(e0, bf_hi(u0), ay);
    }

    float2 bb = ((const float2*)b1)[lane];
    float2 ww = ((const float2*)W2)[lane];
    float r0 = fmaxf(fmaf(dw, ax, bb.x), 0.0f);
    float r1 = fmaxf(fmaf(dw, ay, bb.y), 0.0f);
    float v = r0 * ww.x + r1 * ww.y;
#pragma unroll
    for (int off = 32; off > 0; off >>= 1) v += __shfl_down(v, off);
    if (lane == 0) zs[w] = v * dw;
}

// ---------------- layer-2 aggregation + sigmoid epilogue (ILP-4) ----------------
__global__ void k_agg2_final(const int* __restrict__ eidx,
                             const int* __restrict__ excl,
                             const int* __restrict__ chunkOff,
                             const int* __restrict__ cnt,
                             const float* __restrict__ zs,
                             const float* __restrict__ dinv,
                             const float* __restrict__ b2,
                             float* __restrict__ out) {
    int i = blockIdx.x * 256 + threadIdx.x;
    if (i >= NN) return;
    int offs = excl[i] + chunkOff[i >> 10];
    int c = cnt[i];
    float v = zs[i];   // self-loop
    int j = 0;
    for (; j + 3 < c; j += 4) {
        int s0 = eidx[offs + j + 0];
        int s1 = eidx[offs + j + 1];
        int s2 = eidx[offs + j + 2];
        int s3 = eidx[offs + j + 3];
        v += zs[s0] + zs[s1] + zs[s2] + zs[s3];
    }
    for (; j < c; ++j) v += zs[eidx[offs + j]];
    float z = fmaf(dinv[i], v, b2[0]);
    out[i] = 1.0f / (1.0f + __expf(-z));
}

extern "C" void kernel_launch(void* const* d_in, const int* in_sizes, int n_in,
                              void* d_out, int out_size, void* d_ws, size_t ws_size,
                              hipStream_t stream) {
    const float* x  = (const float*)d_in[0];
    const int*   ei = (const int*)d_in[1];
    const float* W1 = (const float*)d_in[2];
    const float* b1 = (const float*)d_in[3];
    const float* W2 = (const float*)d_in[4];
    const float* b2 = (const float*)d_in[5];
    float* out = (float*)d_out;

    const int E = in_sizes[1] / 2;
    const int* src = ei;
    const int* dst = ei + E;

    // workspace layout (4-byte elements)
    char* wsb = (char*)d_ws;
    float* dinv    = (float*)wsb;                       // N
    int*   cnt     = (int*)(dinv + NN);                 // N
    int*   cnt2    = cnt + NN;                          // N   (contiguous with cnt for memset)
    int*   excl    = cnt2 + NN;                         // N
    float* zs      = (float*)(excl + NN);               // N
    int*   chunkS  = (int*)(zs + NN);                   // 128
    int*   chunkO  = chunkS + 128;                      // 128
    int*   eidx    = chunkO + 128;                      // E
    unsigned short* hs = (unsigned short*)(eidx + E);   // N*128 bf16 (~25.6 MB)

    const int nb_nodes = (NN + 255) / 256;
    const int eb = (E + 1023) / 1024;                   // edge blocks at 4 edges/thread

    hipMemsetAsync(cnt, 0, (size_t)2 * NN * sizeof(int), stream);

    k_gemm_hist<<<GEMM_NB1 + eb, 256, 0, stream>>>(x, W1, hs, dst, E, cnt);

    k_scan1d<<<NCHUNK, 256, 0, stream>>>(cnt, excl, chunkS, dinv);
    k_scan2<<<1, 128, 0, stream>>>(chunkS, chunkO);

    k_gemm_fill<<<GEMM_NB2 + eb, 256, 0, stream>>>(x, W1, hs, src, dst, E,
                                                   excl, chunkO, cnt2, eidx);

    k_agg1l2<<<(NN * 64 + 255) / 256, 256, 0, stream>>>(eidx, excl, chunkO, cnt,
                                                        (const unsigned*)hs, dinv, b1, W2, zs);

    k_agg2_final<<<nb_nodes, 256, 0, stream>>>(eidx, excl, chunkO, cnt, zs, dinv, b2, out);
}

// Round 6
// 393.362 us; speedup vs baseline: 1.0948x; 1.0948x over previous
//
#include <hip/hip_runtime.h>
#include <math.h>

#define NN 100000
#define DIN 256
#define DH 128
#define NCHUNK 98          // ceil(100000/1024)
#define GEMM_NB 1563       // ceil(NN/64)
#define GEMM_NB1 512       // gemm blocks overlapped with hist
#define GEMM_NB2 (GEMM_NB - GEMM_NB1)

using short8  = __attribute__((ext_vector_type(8))) short;
using float4v = __attribute__((ext_vector_type(4))) float;

static __device__ __forceinline__ unsigned short f2bf(float f) {
    unsigned u = __float_as_uint(f);
    unsigned r = u + 0x7fffu + ((u >> 16) & 1u);   // round-to-nearest-even
    return (unsigned short)(r >> 16);
}
static __device__ __forceinline__ float bf_lo(unsigned u) { return __uint_as_float(u << 16); }
static __device__ __forceinline__ float bf_hi(unsigned u) { return __uint_as_float(u & 0xffff0000u); }

// ---------------- GEMM body (MFMA bf16): hs_bf16 = x @ W1 (UNSCALED) ----------------
static __device__ __forceinline__ void gemm_body(int gb, const float* __restrict__ x,
                                                 const float* __restrict__ W1,
                                                 unsigned short* __restrict__ hs) {
    __shared__ unsigned short aL[64 * 32 * 8];   // 32 KB, 16B-chunk XOR swizzle
    const int tid  = threadIdx.x;
    const int wave = tid >> 6;
    const int lane = tid & 63;
    const int quad = lane >> 4;
    const int m16  = lane & 15;
    const int row0 = gb * 64;
    const int n0   = wave * 32;

    short8 bfr[2][8];
#pragma unroll
    for (int ks = 0; ks < 8; ++ks) {
#pragma unroll
        for (int nt = 0; nt < 2; ++nt) {
            short8 v;
            int n = n0 + nt * 16 + m16;
#pragma unroll
            for (int j = 0; j < 8; ++j) {
                float w = W1[(ks * 32 + quad * 8 + j) * DH + n];
                v[j] = (short)f2bf(w);
            }
            bfr[nt][ks] = v;
        }
    }

#pragma unroll
    for (int it = 0; it < 8; ++it) {
        int id  = it * 256 + tid;
        int row = id >> 5;
        int kb  = id & 31;
        int gr  = row0 + row;
        float4 f0, f1;
        if (gr < NN) {
            const float* xp = &x[(long long)gr * DIN + kb * 8];
            f0 = *(const float4*)xp;
            f1 = *(const float4*)(xp + 4);
        } else {
            f0 = make_float4(0.f, 0.f, 0.f, 0.f);
            f1 = f0;
        }
        short8 v;
        v[0] = (short)f2bf(f0.x); v[1] = (short)f2bf(f0.y);
        v[2] = (short)f2bf(f0.z); v[3] = (short)f2bf(f0.w);
        v[4] = (short)f2bf(f1.x); v[5] = (short)f2bf(f1.y);
        v[6] = (short)f2bf(f1.z); v[7] = (short)f2bf(f1.w);
        int chunk = row * 32 + (kb ^ (row & 31));
        *(short8*)&aL[chunk * 8] = v;
    }
    __syncthreads();

    float4v acc[4][2];
#pragma unroll
    for (int mt = 0; mt < 4; ++mt)
#pragma unroll
        for (int nt = 0; nt < 2; ++nt)
            acc[mt][nt] = (float4v)(0.0f);

#pragma unroll
    for (int mt = 0; mt < 4; ++mt) {
        int row = mt * 16 + m16;
#pragma unroll
        for (int ks = 0; ks < 8; ++ks) {
            int kb = ks * 4 + quad;
            int chunk = row * 32 + (kb ^ (row & 31));
            short8 a = *(const short8*)&aL[chunk * 8];
            acc[mt][0] = __builtin_amdgcn_mfma_f32_16x16x32_bf16(a, bfr[0][ks], acc[mt][0], 0, 0, 0);
            acc[mt][1] = __builtin_amdgcn_mfma_f32_16x16x32_bf16(a, bfr[1][ks], acc[mt][1], 0, 0, 0);
        }
    }

#pragma unroll
    for (int mt = 0; mt < 4; ++mt) {
#pragma unroll
        for (int r = 0; r < 4; ++r) {
            int row = row0 + mt * 16 + quad * 4 + r;
            if (row < NN) {
#pragma unroll
                for (int nt = 0; nt < 2; ++nt)
                    hs[(long long)row * DH + n0 + nt * 16 + m16] = f2bf(acc[mt][nt][r]);
            }
        }
    }
}

// ---------------- K1: gemm part-A  ||  dst histogram (1 edge/thread) ----------------
__global__ __launch_bounds__(256) void k_gemm_hist(const float* __restrict__ x,
                                                   const float* __restrict__ W1,
                                                   unsigned short* __restrict__ hs,
                                                   const int* __restrict__ dst, int E,
                                                   int* __restrict__ cnt) {
    if ((int)blockIdx.x < GEMM_NB1) { gemm_body(blockIdx.x, x, W1, hs); return; }
    int e = ((int)blockIdx.x - GEMM_NB1) * 256 + threadIdx.x;
    if (e < E) atomicAdd(&cnt[dst[e]], 1);
}

// ---------------- scan level 1 + dinv fused ----------------
__global__ __launch_bounds__(256) void k_scan1d(const int* __restrict__ cnt,
                                                int* __restrict__ excl,
                                                int* __restrict__ chunkSums,
                                                float* __restrict__ dinv) {
    __shared__ int tmp[256];
    int t = threadIdx.x;
    int i0 = blockIdx.x * 1024 + t * 4;
    int v0 = (i0 + 0 < NN) ? cnt[i0 + 0] : 0;
    int v1 = (i0 + 1 < NN) ? cnt[i0 + 1] : 0;
    int v2 = (i0 + 2 < NN) ? cnt[i0 + 2] : 0;
    int v3 = (i0 + 3 < NN) ? cnt[i0 + 3] : 0;
    int s0 = v0, s1 = s0 + v1, s2 = s1 + v2, s3 = s2 + v3;
    tmp[t] = s3;
    __syncthreads();
    for (int off = 1; off < 256; off <<= 1) {
        int val = (t >= off) ? tmp[t - off] : 0;
        __syncthreads();
        tmp[t] += val;
        __syncthreads();
    }
    int prev = (t > 0) ? tmp[t - 1] : 0;
    if (i0 + 0 < NN) { excl[i0 + 0] = prev;      dinv[i0 + 0] = rsqrtf(1.0f + (float)v0); }
    if (i0 + 1 < NN) { excl[i0 + 1] = prev + s0; dinv[i0 + 1] = rsqrtf(1.0f + (float)v1); }
    if (i0 + 2 < NN) { excl[i0 + 2] = prev + s1; dinv[i0 + 2] = rsqrtf(1.0f + (float)v2); }
    if (i0 + 3 < NN) { excl[i0 + 3] = prev + s2; dinv[i0 + 3] = rsqrtf(1.0f + (float)v3); }
    if (t == 255) chunkSums[blockIdx.x] = tmp[255];
}

__global__ __launch_bounds__(128) void k_scan2(const int* __restrict__ chunkSums,
                                               int* __restrict__ chunkOff) {
    __shared__ int tmp[128];
    int t = threadIdx.x;
    tmp[t] = (t < NCHUNK) ? chunkSums[t] : 0;
    __syncthreads();
    for (int off = 1; off < 128; off <<= 1) {
        int val = (t >= off) ? tmp[t - off] : 0;
        __syncthreads();
        tmp[t] += val;
        __syncthreads();
    }
    chunkOff[t] = (t > 0) ? tmp[t - 1] : 0;
}

// ---------------- absolute offsets: excl += chunkOff; cnt2 = excl ----------------
__global__ void k_absfix(int* __restrict__ excl, const int* __restrict__ chunkOff,
                         int* __restrict__ cnt2) {
    int i = blockIdx.x * 256 + threadIdx.x;
    if (i < NN) {
        int a = excl[i] + chunkOff[i >> 10];
        excl[i] = a;
        cnt2[i] = a;
    }
}

// ---------------- K4: gemm part-B  ||  CSR fill (1 edge/thread, 2 random ops) ----------------
__global__ __launch_bounds__(256) void k_gemm_fill(const float* __restrict__ x,
                                                   const float* __restrict__ W1,
                                                   unsigned short* __restrict__ hs,
                                                   const int* __restrict__ src,
                                                   const int* __restrict__ dst, int E,
                                                   int* __restrict__ cnt2,
                                                   int* __restrict__ eidx) {
    if ((int)blockIdx.x < GEMM_NB2) { gemm_body(GEMM_NB1 + blockIdx.x, x, W1, hs); return; }
    int e = ((int)blockIdx.x - GEMM_NB2) * 256 + threadIdx.x;
    if (e >= E) return;
    int slot = atomicAdd(&cnt2[dst[e]], 1);   // cnt2 pre-seeded with absolute base offset
    eidx[slot] = src[e];
}

// ---------------- fused layer-1 aggregation + layer-2 linear: one wave per node ----------------
__global__ __launch_bounds__(256) void k_agg1l2(const int* __restrict__ eidx,
                                                const int* __restrict__ excl,   // absolute
                                                const int* __restrict__ cnt,
                                                const unsigned* __restrict__ hs2,
                                                const float* __restrict__ dinv,
                                                const float* __restrict__ b1,
                                                const float* __restrict__ W2,
                                                float* __restrict__ zs) {
    int w = (blockIdx.x * 256 + threadIdx.x) >> 6;
    if (w >= NN) return;
    int lane = threadIdx.x & 63;
    int offs = excl[w];
    int c = cnt[w];

    float dw = dinv[w];
    unsigned u = hs2[(long long)w * 64 + lane];   // self-loop
    float ax = dw * bf_lo(u);
    float ay = dw * bf_hi(u);

    int j = 0;
    for (; j + 7 < c; j += 8) {
        int s[8]; float es[8]; unsigned uu[8];
#pragma unroll
        for (int q = 0; q < 8; ++q) s[q] = eidx[offs + j + q];
#pragma unroll
        for (int q = 0; q < 8; ++q) es[q] = dinv[s[q]];
#pragma unroll
        for (int q = 0; q < 8; ++q) uu[q] = hs2[(long long)s[q] * 64 + lane];
#pragma unroll
        for (int q = 0; q < 8; ++q) {
            ax = fmaf(es[q], bf_lo(uu[q]), ax);
            ay = fmaf(es[q], bf_hi(uu[q]), ay);
        }
    }
    for (; j + 1 < c; j += 2) {
        int s0 = eidx[offs + j], s1 = eidx[offs + j + 1];
        float e0 = dinv[s0], e1 = dinv[s1];
        unsigned u0 = hs2[(long long)s0 * 64 + lane];
        unsigned u1 = hs2[(long long)s1 * 64 + lane];
        ax = fmaf(e0, bf_lo(u0), ax); ay = fmaf(e0, bf_hi(u0), ay);
        ax = fmaf(e1, bf_lo(u1), ax); ay = fmaf(e1, bf_hi(u1), ay);
    }
    if (j < c) {
        int s0 = eidx[offs + j];
        float e0 = dinv[s0];
        unsigned u0 = hs2[(long long)s0 * 64 + lane];
        ax = fmaf(e0, bf_lo(u0), ax); ay = fmaf(e0, bf_hi(u0), ay);
    }

    float2 bb = ((const float2*)b1)[lane];
    float2 ww = ((const float2*)W2)[lane];
    float r0 = fmaxf(fmaf(dw, ax, bb.x), 0.0f);
    float r1 = fmaxf(fmaf(dw, ay, bb.y), 0.0f);
    float v = r0 * ww.x + r1 * ww.y;
#pragma unroll
    for (int off = 32; off > 0; off >>= 1) v += __shfl_down(v, off);
    if (lane == 0) zs[w] = v * dw;
}

// ---------------- layer-2 aggregation + sigmoid epilogue (ILP-4) ----------------
__global__ void k_agg2_final(const int* __restrict__ eidx,
                             const int* __restrict__ excl,   // absolute
                             const int* __restrict__ cnt,
                             const float* __restrict__ zs,
                             const float* __restrict__ dinv,
                             const float* __restrict__ b2,
                             float* __restrict__ out) {
    int i = blockIdx.x * 256 + threadIdx.x;
    if (i >= NN) return;
    int offs = excl[i];
    int c = cnt[i];
    float v = zs[i];   // self-loop
    int j = 0;
    for (; j + 3 < c; j += 4) {
        int s0 = eidx[offs + j + 0];
        int s1 = eidx[offs + j + 1];
        int s2 = eidx[offs + j + 2];
        int s3 = eidx[offs + j + 3];
        v += zs[s0] + zs[s1] + zs[s2] + zs[s3];
    }
    for (; j < c; ++j) v += zs[eidx[offs + j]];
    float z = fmaf(dinv[i], v, b2[0]);
    out[i] = 1.0f / (1.0f + __expf(-z));
}

extern "C" void kernel_launch(void* const* d_in, const int* in_sizes, int n_in,
                              void* d_out, int out_size, void* d_ws, size_t ws_size,
                              hipStream_t stream) {
    const float* x  = (const float*)d_in[0];
    const int*   ei = (const int*)d_in[1];
    const float* W1 = (const float*)d_in[2];
    const float* b1 = (const float*)d_in[3];
    const float* W2 = (const float*)d_in[4];
    const float* b2 = (const float*)d_in[5];
    float* out = (float*)d_out;

    const int E = in_sizes[1] / 2;
    const int* src = ei;
    const int* dst = ei + E;

    // workspace layout (4-byte elements)
    char* wsb = (char*)d_ws;
    float* dinv    = (float*)wsb;                       // N
    int*   cnt     = (int*)(dinv + NN);                 // N
    int*   cnt2    = cnt + NN;                          // N
    int*   excl    = cnt2 + NN;                         // N
    float* zs      = (float*)(excl + NN);               // N
    int*   chunkS  = (int*)(zs + NN);                   // 128
    int*   chunkO  = chunkS + 128;                      // 128
    int*   eidx    = chunkO + 128;                      // E
    unsigned short* hs = (unsigned short*)(eidx + E);   // N*128 bf16 (~25.6 MB)

    const int nb_nodes = (NN + 255) / 256;
    const int nb_edges = (E + 255) / 256;

    hipMemsetAsync(cnt, 0, (size_t)NN * sizeof(int), stream);

    k_gemm_hist<<<GEMM_NB1 + nb_edges, 256, 0, stream>>>(x, W1, hs, dst, E, cnt);

    k_scan1d<<<NCHUNK, 256, 0, stream>>>(cnt, excl, chunkS, dinv);
    k_scan2<<<1, 128, 0, stream>>>(chunkS, chunkO);
    k_absfix<<<nb_nodes, 256, 0, stream>>>(excl, chunkO, cnt2);

    k_gemm_fill<<<GEMM_NB2 + nb_edges, 256, 0, stream>>>(x, W1, hs, src, dst, E,
                                                         cnt2, eidx);

    k_agg1l2<<<(NN * 64 + 255) / 256, 256, 0, stream>>>(eidx, excl, cnt,
                                                        (const unsigned*)hs, dinv, b1, W2, zs);

    k_agg2_final<<<nb_nodes, 256, 0, stream>>>(eidx, excl, cnt, zs, dinv, b2, out);
}

// Round 7
// 309.259 us; speedup vs baseline: 1.3925x; 1.2720x over previous
//
#include <hip/hip_runtime.h>
#include <math.h>

#define NN 100000
#define DIN 256
#define DH 128
#define GEMM_NB 1563       // ceil(NN/64)
#define GEMM_NB1 512       // gemm blocks overlapped with partition pass A
#define GEMM_NB2 (GEMM_NB - GEMM_NB1)
#define BSHIFT 9
#define BNODES 512                     // nodes per bucket
#define NB_BUCKET 196                  // ceil(NN/512)
#define BCAP 12288                     // bucket capacity (mean 8192, sigma ~90 -> 45 sigma margin)
#define PA_EDGES 4096                  // edges per pass-A block

using short8  = __attribute__((ext_vector_type(8))) short;
using float4v = __attribute__((ext_vector_type(4))) float;

static __device__ __forceinline__ unsigned short f2bf(float f) {
    unsigned u = __float_as_uint(f);
    unsigned r = u + 0x7fffu + ((u >> 16) & 1u);   // round-to-nearest-even
    return (unsigned short)(r >> 16);
}
static __device__ __forceinline__ float bf_lo(unsigned u) { return __uint_as_float(u << 16); }
static __device__ __forceinline__ float bf_hi(unsigned u) { return __uint_as_float(u & 0xffff0000u); }

// ---------------- GEMM body (MFMA bf16): hs_bf16 = x @ W1 (UNSCALED) ----------------
static __device__ __forceinline__ void gemm_body(int gb, const float* __restrict__ x,
                                                 const float* __restrict__ W1,
                                                 unsigned short* __restrict__ hs) {
    __shared__ unsigned short aL[64 * 32 * 8];   // 32 KB, 16B-chunk XOR swizzle
    const int tid  = threadIdx.x;
    const int wave = tid >> 6;
    const int lane = tid & 63;
    const int quad = lane >> 4;
    const int m16  = lane & 15;
    const int row0 = gb * 64;
    const int n0   = wave * 32;

    short8 bfr[2][8];
#pragma unroll
    for (int ks = 0; ks < 8; ++ks) {
#pragma unroll
        for (int nt = 0; nt < 2; ++nt) {
            short8 v;
            int n = n0 + nt * 16 + m16;
#pragma unroll
            for (int j = 0; j < 8; ++j) {
                float w = W1[(ks * 32 + quad * 8 + j) * DH + n];
                v[j] = (short)f2bf(w);
            }
            bfr[nt][ks] = v;
        }
    }

#pragma unroll
    for (int it = 0; it < 8; ++it) {
        int id  = it * 256 + tid;
        int row = id >> 5;
        int kb  = id & 31;
        int gr  = row0 + row;
        float4 f0, f1;
        if (gr < NN) {
            const float* xp = &x[(long long)gr * DIN + kb * 8];
            f0 = *(const float4*)xp;
            f1 = *(const float4*)(xp + 4);
        } else {
            f0 = make_float4(0.f, 0.f, 0.f, 0.f);
            f1 = f0;
        }
        short8 v;
        v[0] = (short)f2bf(f0.x); v[1] = (short)f2bf(f0.y);
        v[2] = (short)f2bf(f0.z); v[3] = (short)f2bf(f0.w);
        v[4] = (short)f2bf(f1.x); v[5] = (short)f2bf(f1.y);
        v[6] = (short)f2bf(f1.z); v[7] = (short)f2bf(f1.w);
        int chunk = row * 32 + (kb ^ (row & 31));
        *(short8*)&aL[chunk * 8] = v;
    }
    __syncthreads();

    float4v acc[4][2];
#pragma unroll
    for (int mt = 0; mt < 4; ++mt)
#pragma unroll
        for (int nt = 0; nt < 2; ++nt)
            acc[mt][nt] = (float4v)(0.0f);

#pragma unroll
    for (int mt = 0; mt < 4; ++mt) {
        int row = mt * 16 + m16;
#pragma unroll
        for (int ks = 0; ks < 8; ++ks) {
            int kb = ks * 4 + quad;
            int chunk = row * 32 + (kb ^ (row & 31));
            short8 a = *(const short8*)&aL[chunk * 8];
            acc[mt][0] = __builtin_amdgcn_mfma_f32_16x16x32_bf16(a, bfr[0][ks], acc[mt][0], 0, 0, 0);
            acc[mt][1] = __builtin_amdgcn_mfma_f32_16x16x32_bf16(a, bfr[1][ks], acc[mt][1], 0, 0, 0);
        }
    }

#pragma unroll
    for (int mt = 0; mt < 4; ++mt) {
#pragma unroll
        for (int r = 0; r < 4; ++r) {
            int row = row0 + mt * 16 + quad * 4 + r;
            if (row < NN) {
#pragma unroll
                for (int nt = 0; nt < 2; ++nt)
                    hs[(long long)row * DH + n0 + nt * 16 + m16] = f2bf(acc[mt][nt][r]);
            }
        }
    }
}

// ---------------- pass A body: partition 4096 edges into dst-range buckets ----------------
static __device__ __forceinline__ void partA_body(int pb, const int* __restrict__ src,
                                                  const int* __restrict__ dst, int E,
                                                  int* __restrict__ bucketFill,
                                                  int2* __restrict__ bucketArr) {
    __shared__ int aCnt[NB_BUCKET];   // per-block per-bucket count, then cursor
    __shared__ int aBase[NB_BUCKET];  // reserved global base within bucket
    const int tid = threadIdx.x;
    for (int i = tid; i < NB_BUCKET; i += 256) aCnt[i] = 0;
    __syncthreads();
    const int e0   = pb * PA_EDGES;
    const int eend = min(e0 + PA_EDGES, E);
    for (int e = e0 + tid; e < eend; e += 256)
        atomicAdd(&aCnt[dst[e] >> BSHIFT], 1);
    __syncthreads();
    for (int i = tid; i < NB_BUCKET; i += 256) {
        int c = aCnt[i];
        aBase[i] = c ? atomicAdd(&bucketFill[i], c) : 0;
        aCnt[i] = 0;   // reuse as write cursor
    }
    __syncthreads();
    for (int e = e0 + tid; e < eend; e += 256) {
        int d = dst[e];
        int b = d >> BSHIFT;
        int r = atomicAdd(&aCnt[b], 1);
        bucketArr[(long long)b * BCAP + aBase[b] + r] = make_int2(src[e], d);
    }
}

// ---------------- K1: pass A  ||  gemm part 1 ----------------
__global__ __launch_bounds__(256) void k_partA_gemm(const int* __restrict__ src,
                                                    const int* __restrict__ dst, int E,
                                                    int* __restrict__ bucketFill,
                                                    int2* __restrict__ bucketArr,
                                                    int pa_nb,
                                                    const float* __restrict__ x,
                                                    const float* __restrict__ W1,
                                                    unsigned short* __restrict__ hs) {
    if ((int)blockIdx.x < pa_nb) partA_body(blockIdx.x, src, dst, E, bucketFill, bucketArr);
    else                         gemm_body((int)blockIdx.x - pa_nb, x, W1, hs);
}

// ---------------- bucket-size exclusive scan (1 block) ----------------
__global__ __launch_bounds__(256) void k_bscan(const int* __restrict__ bucketFill,
                                               int* __restrict__ bucketScan) {
    __shared__ int st[256];
    int t = threadIdx.x;
    st[t] = (t < NB_BUCKET) ? bucketFill[t] : 0;
    __syncthreads();
    for (int off = 1; off < 256; off <<= 1) {
        int val = (t >= off) ? st[t - off] : 0;
        __syncthreads();
        st[t] += val;
        __syncthreads();
    }
    bucketScan[t] = (t > 0) ? st[t - 1] : 0;
}

// ---------------- pass B body: per-bucket local CSR build ----------------
static __device__ __forceinline__ void partB_body(int b,
                                                  const int* __restrict__ bucketFill,
                                                  const int* __restrict__ bucketScan,
                                                  const int2* __restrict__ bucketArr,
                                                  int* __restrict__ cnt,
                                                  int* __restrict__ excl,
                                                  float* __restrict__ dinv,
                                                  int* __restrict__ eidx) {
    __shared__ int h[BNODES];     // hist, then cursor
    __shared__ int hex[BNODES];   // exclusive prefix within bucket
    __shared__ int st[256];
    const int tid   = threadIdx.x;
    const int nbase = b << BSHIFT;
    const int len   = bucketFill[b];
    const int gbase = bucketScan[b];
    const long long abase = (long long)b * BCAP;

    for (int i = tid; i < BNODES; i += 256) h[i] = 0;
    __syncthreads();
    for (int k = tid; k < len; k += 256)
        atomicAdd(&h[bucketArr[abase + k].y - nbase], 1);
    __syncthreads();

    // scan 512 counters: pairwise + Hillis-Steele over 256 pair sums
    int a0 = h[2 * tid], a1 = h[2 * tid + 1];
    st[tid] = a0 + a1;
    __syncthreads();
    for (int off = 1; off < 256; off <<= 1) {
        int val = (tid >= off) ? st[tid - off] : 0;
        __syncthreads();
        st[tid] += val;
        __syncthreads();
    }
    int prev = (tid > 0) ? st[tid - 1] : 0;
    hex[2 * tid]     = prev;
    hex[2 * tid + 1] = prev + a0;
    __syncthreads();

    // emit per-node CSR meta
    for (int i = tid; i < BNODES; i += 256) {
        int n = nbase + i;
        if (n < NN) {
            int c = h[i];
            cnt[n]  = c;
            excl[n] = gbase + hex[i];
            dinv[n] = rsqrtf(1.0f + (float)c);
        }
    }
    for (int i = tid; i < BNODES; i += 256) h[i] = 0;   // cursors
    __syncthreads();

    // place edges
    for (int k = tid; k < len; k += 256) {
        int2 p = bucketArr[abase + k];
        int li = p.y - nbase;
        int r = atomicAdd(&h[li], 1);
        eidx[gbase + hex[li] + r] = p.x;
    }
}

// ---------------- K3: pass B  ||  gemm part 2 ----------------
__global__ __launch_bounds__(256) void k_partB_gemm(const int* __restrict__ bucketFill,
                                                    const int* __restrict__ bucketScan,
                                                    const int2* __restrict__ bucketArr,
                                                    int* __restrict__ cnt,
                                                    int* __restrict__ excl,
                                                    float* __restrict__ dinv,
                                                    int* __restrict__ eidx,
                                                    const float* __restrict__ x,
                                                    const float* __restrict__ W1,
                                                    unsigned short* __restrict__ hs) {
    if ((int)blockIdx.x < NB_BUCKET)
        partB_body(blockIdx.x, bucketFill, bucketScan, bucketArr, cnt, excl, dinv, eidx);
    else
        gemm_body(GEMM_NB1 + (int)blockIdx.x - NB_BUCKET, x, W1, hs);
}

// ---------------- fused layer-1 aggregation + layer-2 linear: one wave per node ----------------
__global__ __launch_bounds__(256) void k_agg1l2(const int* __restrict__ eidx,
                                                const int* __restrict__ excl,   // absolute
                                                const int* __restrict__ cnt,
                                                const unsigned* __restrict__ hs2,
                                                const float* __restrict__ dinv,
                                                const float* __restrict__ b1,
                                                const float* __restrict__ W2,
                                                float* __restrict__ zs) {
    int w = (blockIdx.x * 256 + threadIdx.x) >> 6;
    if (w >= NN) return;
    int lane = threadIdx.x & 63;
    int offs = excl[w];
    int c = cnt[w];

    float dw = dinv[w];
    unsigned u = hs2[(long long)w * 64 + lane];   // self-loop
    float ax = dw * bf_lo(u);
    float ay = dw * bf_hi(u);

    int j = 0;
    for (; j + 7 < c; j += 8) {
        int s[8]; float es[8]; unsigned uu[8];
#pragma unroll
        for (int q = 0; q < 8; ++q) s[q] = eidx[offs + j + q];
#pragma unroll
        for (int q = 0; q < 8; ++q) es[q] = dinv[s[q]];
#pragma unroll
        for (int q = 0; q < 8; ++q) uu[q] = hs2[(long long)s[q] * 64 + lane];
#pragma unroll
        for (int q = 0; q < 8; ++q) {
            ax = fmaf(es[q], bf_lo(uu[q]), ax);
            ay = fmaf(es[q], bf_hi(uu[q]), ay);
        }
    }
    for (; j + 1 < c; j += 2) {
        int s0 = eidx[offs + j], s1 = eidx[offs + j + 1];
        float e0 = dinv[s0], e1 = dinv[s1];
        unsigned u0 = hs2[(long long)s0 * 64 + lane];
        unsigned u1 = hs2[(long long)s1 * 64 + lane];
        ax = fmaf(e0, bf_lo(u0), ax); ay = fmaf(e0, bf_hi(u0), ay);
        ax = fmaf(e1, bf_lo(u1), ax); ay = fmaf(e1, bf_hi(u1), ay);
    }
    if (j < c) {
        int s0 = eidx[offs + j];
        float e0 = dinv[s0];
        unsigned u0 = hs2[(long long)s0 * 64 + lane];
        ax = fmaf(e0, bf_lo(u0), ax); ay = fmaf(e0, bf_hi(u0), ay);
    }

    float2 bb = ((const float2*)b1)[lane];
    float2 ww = ((const float2*)W2)[lane];
    float r0 = fmaxf(fmaf(dw, ax, bb.x), 0.0f);
    float r1 = fmaxf(fmaf(dw, ay, bb.y), 0.0f);
    float v = r0 * ww.x + r1 * ww.y;
#pragma unroll
    for (int off = 32; off > 0; off >>= 1) v += __shfl_down(v, off);
    if (lane == 0) zs[w] = v * dw;
}

// ---------------- layer-2 aggregation + sigmoid epilogue (ILP-4) ----------------
__global__ void k_agg2_final(const int* __restrict__ eidx,
                             const int* __restrict__ excl,   // absolute
                             const int* __restrict__ cnt,
                             const float* __restrict__ zs,
                             const float* __restrict__ dinv,
                             const float* __restrict__ b2,
                             float* __restrict__ out) {
    int i = blockIdx.x * 256 + threadIdx.x;
    if (i >= NN) return;
    int offs = excl[i];
    int c = cnt[i];
    float v = zs[i];   // self-loop
    int j = 0;
    for (; j + 3 < c; j += 4) {
        int s0 = eidx[offs + j + 0];
        int s1 = eidx[offs + j + 1];
        int s2 = eidx[offs + j + 2];
        int s3 = eidx[offs + j + 3];
        v += zs[s0] + zs[s1] + zs[s2] + zs[s3];
    }
    for (; j < c; ++j) v += zs[eidx[offs + j]];
    float z = fmaf(dinv[i], v, b2[0]);
    out[i] = 1.0f / (1.0f + __expf(-z));
}

extern "C" void kernel_launch(void* const* d_in, const int* in_sizes, int n_in,
                              void* d_out, int out_size, void* d_ws, size_t ws_size,
                              hipStream_t stream) {
    const float* x  = (const float*)d_in[0];
    const int*   ei = (const int*)d_in[1];
    const float* W1 = (const float*)d_in[2];
    const float* b1 = (const float*)d_in[3];
    const float* W2 = (const float*)d_in[4];
    const float* b2 = (const float*)d_in[5];
    float* out = (float*)d_out;

    const int E = in_sizes[1] / 2;
    const int* src = ei;
    const int* dst = ei + E;

    // workspace layout (4-byte elements; bucketArr needs 8B alignment)
    int* wsi = (int*)d_ws;
    float* dinv       = (float*)wsi;                 // N
    int*   cnt        = wsi + NN;                    // N
    int*   excl       = cnt + NN;                    // N
    float* zs         = (float*)(excl + NN);         // N
    int*   bucketFill = (int*)(zs + NN);             // 256
    int*   bucketScan = bucketFill + 256;            // 256
    int*   eidx       = bucketScan + 256;            // E   (offset 400512 ints = 1602048 B, 8B aligned)
    int2*  bucketArr  = (int2*)(eidx + E);           // NB_BUCKET*BCAP pairs (~19.3 MB)
    unsigned short* hs = (unsigned short*)(bucketArr + (long long)NB_BUCKET * BCAP);  // N*128 bf16

    const int nb_nodes = (NN + 255) / 256;
    const int pa_nb = (E + PA_EDGES - 1) / PA_EDGES;

    hipMemsetAsync(bucketFill, 0, NB_BUCKET * sizeof(int), stream);

    k_partA_gemm<<<pa_nb + GEMM_NB1, 256, 0, stream>>>(src, dst, E, bucketFill, bucketArr,
                                                       pa_nb, x, W1, hs);

    k_bscan<<<1, 256, 0, stream>>>(bucketFill, bucketScan);

    k_partB_gemm<<<NB_BUCKET + GEMM_NB2, 256, 0, stream>>>(bucketFill, bucketScan, bucketArr,
                                                           cnt, excl, dinv, eidx, x, W1, hs);

    k_agg1l2<<<(NN * 64 + 255) / 256, 256, 0, stream>>>(eidx, excl, cnt,
                                                        (const unsigned*)hs, dinv, b1, W2, zs);

    k_agg2_final<<<nb_nodes, 256, 0, stream>>>(eidx, excl, cnt, zs, dinv, b2, out);
}

// Round 8
// 300.672 us; speedup vs baseline: 1.4323x; 1.0286x over previous
//
#include <hip/hip_runtime.h>
#include <math.h>

#define NN 100000
#define DIN 256
#define DH 128
#define GEMM_NB 1563       // ceil(NN/64)
#define BSHIFT 9
#define BNODES 512                     // nodes per bucket
#define NB_BUCKET 196                  // ceil(NN/512)
#define BCAP 12288                     // bucket capacity (mean 8163, sigma ~90)
#define PA_EDGES 8192                  // edges per pass-A block

using short8  = __attribute__((ext_vector_type(8))) short;
using float4v = __attribute__((ext_vector_type(4))) float;

static __device__ __forceinline__ unsigned short f2bf(float f) {
    unsigned u = __float_as_uint(f);
    unsigned r = u + 0x7fffu + ((u >> 16) & 1u);   // round-to-nearest-even
    return (unsigned short)(r >> 16);
}
static __device__ __forceinline__ float bf_lo(unsigned u) { return __uint_as_float(u << 16); }
static __device__ __forceinline__ float bf_hi(unsigned u) { return __uint_as_float(u & 0xffff0000u); }

// ---------------- W1 -> bf16 fragment-order pre-swizzle ----------------
// slot t = ((wave*2+nt)*8+ks)*64 + lane ; stores 8 bf16: j=0..7 of
// W1[(ks*32 + (lane>>4)*8 + j)*128 + wave*32 + nt*16 + (lane&15)]
__global__ __launch_bounds__(256) void k_prepW(const float* __restrict__ W1,
                                               unsigned short* __restrict__ W1p) {
    int t = blockIdx.x * 256 + threadIdx.x;     // 0..32767
    int lane = t & 63;
    int ks   = (t >> 6) & 7;
    int nt   = (t >> 9) & 1;
    int wv   = (t >> 10) & 3;
    int n = wv * 32 + nt * 16 + (lane & 15);
    int kbase = ks * 32 + (lane >> 4) * 8;
    short8 v;
#pragma unroll
    for (int j = 0; j < 8; ++j) v[j] = (short)f2bf(W1[(kbase + j) * DH + n]);
    *(short8*)&W1p[(long long)t * 8] = v;
}

// ---------------- standalone GEMM (MFMA bf16): hs_bf16 = x @ W1 (UNSCALED) ----------------
__global__ __launch_bounds__(256) void k_gemm(const float* __restrict__ x,
                                              const unsigned short* __restrict__ W1p,
                                              unsigned short* __restrict__ hs) {
    __shared__ unsigned short aL[64 * 32 * 8];   // 32 KB, 16B-chunk XOR swizzle
    const int tid  = threadIdx.x;
    const int wave = tid >> 6;
    const int lane = tid & 63;
    const int quad = lane >> 4;
    const int m16  = lane & 15;
    const int row0 = blockIdx.x * 64;

    // coalesced fragment loads: 16 x 16B per thread
    short8 bfr[2][8];
#pragma unroll
    for (int nt = 0; nt < 2; ++nt)
#pragma unroll
        for (int ks = 0; ks < 8; ++ks)
            bfr[nt][ks] = ((const short8*)W1p)[((wave * 2 + nt) * 8 + ks) * 64 + lane];

    // stage A tile -> bf16 LDS, swizzled
#pragma unroll
    for (int it = 0; it < 8; ++it) {
        int id  = it * 256 + tid;
        int row = id >> 5;
        int kb  = id & 31;
        int gr  = row0 + row;
        float4 f0, f1;
        if (gr < NN) {
            const float* xp = &x[(long long)gr * DIN + kb * 8];
            f0 = *(const float4*)xp;
            f1 = *(const float4*)(xp + 4);
        } else {
            f0 = make_float4(0.f, 0.f, 0.f, 0.f);
            f1 = f0;
        }
        short8 v;
        v[0] = (short)f2bf(f0.x); v[1] = (short)f2bf(f0.y);
        v[2] = (short)f2bf(f0.z); v[3] = (short)f2bf(f0.w);
        v[4] = (short)f2bf(f1.x); v[5] = (short)f2bf(f1.y);
        v[6] = (short)f2bf(f1.z); v[7] = (short)f2bf(f1.w);
        int chunk = row * 32 + (kb ^ (row & 31));
        *(short8*)&aL[chunk * 8] = v;
    }
    __syncthreads();

    float4v acc[4][2];
#pragma unroll
    for (int mt = 0; mt < 4; ++mt)
#pragma unroll
        for (int nt = 0; nt < 2; ++nt)
            acc[mt][nt] = (float4v)(0.0f);

#pragma unroll
    for (int mt = 0; mt < 4; ++mt) {
        int row = mt * 16 + m16;
#pragma unroll
        for (int ks = 0; ks < 8; ++ks) {
            int kb = ks * 4 + quad;
            int chunk = row * 32 + (kb ^ (row & 31));
            short8 a = *(const short8*)&aL[chunk * 8];
            acc[mt][0] = __builtin_amdgcn_mfma_f32_16x16x32_bf16(a, bfr[0][ks], acc[mt][0], 0, 0, 0);
            acc[mt][1] = __builtin_amdgcn_mfma_f32_16x16x32_bf16(a, bfr[1][ks], acc[mt][1], 0, 0, 0);
        }
    }

    const int n0 = wave * 32;
#pragma unroll
    for (int mt = 0; mt < 4; ++mt) {
#pragma unroll
        for (int r = 0; r < 4; ++r) {
            int row = row0 + mt * 16 + quad * 4 + r;
            if (row < NN) {
#pragma unroll
                for (int nt = 0; nt < 2; ++nt)
                    hs[(long long)row * DH + n0 + nt * 16 + m16] = f2bf(acc[mt][nt][r]);
            }
        }
    }
}

// ---------------- pass A: partition 8192 edges into dst-range buckets ----------------
__global__ __launch_bounds__(512) void k_partA(const int* __restrict__ src,
                                               const int* __restrict__ dst, int E,
                                               int* __restrict__ bucketFill,
                                               int2* __restrict__ bucketArr) {
    __shared__ int aCnt[NB_BUCKET];
    __shared__ int aBase[NB_BUCKET];
    const int tid = threadIdx.x;
    for (int i = tid; i < NB_BUCKET; i += 512) aCnt[i] = 0;
    __syncthreads();
    const int e0   = blockIdx.x * PA_EDGES;
    const int eend = min(e0 + PA_EDGES, E);
    for (int e = e0 + tid; e < eend; e += 512)
        atomicAdd(&aCnt[dst[e] >> BSHIFT], 1);
    __syncthreads();
    for (int i = tid; i < NB_BUCKET; i += 512) {
        int c = aCnt[i];
        aBase[i] = c ? atomicAdd(&bucketFill[i], c) : 0;
        aCnt[i] = 0;   // reuse as cursor
    }
    __syncthreads();
    for (int e = e0 + tid; e < eend; e += 512) {
        int d = dst[e];
        int b = d >> BSHIFT;
        int r = atomicAdd(&aCnt[b], 1);
        bucketArr[(long long)b * BCAP + aBase[b] + r] = make_int2(src[e], d);
    }
}

// ---------------- pass B: per-bucket local CSR build (one block per bucket) ----------------
__global__ __launch_bounds__(512) void k_partB(const int* __restrict__ bucketFill,
                                               const int2* __restrict__ bucketArr,
                                               int* __restrict__ cnt,
                                               int* __restrict__ excl,
                                               float* __restrict__ dinv,
                                               int* __restrict__ eidx) {
    __shared__ int h[BNODES];     // hist, then cursor
    __shared__ int hex[BNODES];   // exclusive prefix within bucket
    __shared__ int st[256];
    const int tid   = threadIdx.x;
    const int b     = blockIdx.x;
    const int nbase = b << BSHIFT;
    const int len   = bucketFill[b];
    const long long abase = (long long)b * BCAP;

    // gbase = sum(bucketFill[0..b-1]) via block reduction
    if (tid < 256) st[tid] = (tid < b) ? bucketFill[tid] : 0;
    __syncthreads();
    for (int off = 128; off > 0; off >>= 1) {
        if (tid < off) st[tid] += st[tid + off];
        __syncthreads();
    }
    const int gbase = st[0];
    __syncthreads();

    for (int i = tid; i < BNODES; i += 512) h[i] = 0;
    __syncthreads();
    for (int k = tid; k < len; k += 512)
        atomicAdd(&h[bucketArr[abase + k].y - nbase], 1);
    __syncthreads();

    // scan 512 counters: pairwise + Hillis-Steele over 256 pair sums
    int a0 = 0, a1 = 0;
    if (tid < 256) {
        a0 = h[2 * tid]; a1 = h[2 * tid + 1];
        st[tid] = a0 + a1;
    }
    __syncthreads();
    for (int off = 1; off < 256; off <<= 1) {
        int val = (tid < 256 && tid >= off) ? st[tid - off] : 0;
        __syncthreads();
        if (tid < 256) st[tid] += val;
        __syncthreads();
    }
    if (tid < 256) {
        int prev = (tid > 0) ? st[tid - 1] : 0;
        hex[2 * tid]     = prev;
        hex[2 * tid + 1] = prev + a0;
    }
    __syncthreads();

    for (int i = tid; i < BNODES; i += 512) {
        int n = nbase + i;
        if (n < NN) {
            int c = h[i];
            cnt[n]  = c;
            excl[n] = gbase + hex[i];
            dinv[n] = rsqrtf(1.0f + (float)c);
        }
    }
    for (int i = tid; i < BNODES; i += 512) h[i] = 0;   // cursors
    __syncthreads();

    for (int k = tid; k < len; k += 512) {
        int2 p = bucketArr[abase + k];
        int li = p.y - nbase;
        int r = atomicAdd(&h[li], 1);
        eidx[gbase + hex[li] + r] = p.x;
    }
}

// ---------------- fused layer-1 aggregation + layer-2 linear: one wave per node ----------------
__global__ __launch_bounds__(256) void k_agg1l2(const int* __restrict__ eidx,
                                                const int* __restrict__ excl,   // absolute
                                                const int* __restrict__ cnt,
                                                const unsigned* __restrict__ hs2,
                                                const float* __restrict__ dinv,
                                                const float* __restrict__ b1,
                                                const float* __restrict__ W2,
                                                float* __restrict__ zs) {
    int w = (blockIdx.x * 256 + threadIdx.x) >> 6;
    if (w >= NN) return;
    int lane = threadIdx.x & 63;
    int offs = excl[w];
    int c = cnt[w];

    float dw = dinv[w];
    unsigned u = hs2[(long long)w * 64 + lane];   // self-loop
    float ax = dw * bf_lo(u);
    float ay = dw * bf_hi(u);

    int j = 0;
    for (; j + 7 < c; j += 8) {
        int s[8]; float es[8]; unsigned uu[8];
#pragma unroll
        for (int q = 0; q < 8; ++q) s[q] = eidx[offs + j + q];
#pragma unroll
        for (int q = 0; q < 8; ++q) es[q] = dinv[s[q]];
#pragma unroll
        for (int q = 0; q < 8; ++q) uu[q] = hs2[(long long)s[q] * 64 + lane];
#pragma unroll
        for (int q = 0; q < 8; ++q) {
            ax = fmaf(es[q], bf_lo(uu[q]), ax);
            ay = fmaf(es[q], bf_hi(uu[q]), ay);
        }
    }
    for (; j + 1 < c; j += 2) {
        int s0 = eidx[offs + j], s1 = eidx[offs + j + 1];
        float e0 = dinv[s0], e1 = dinv[s1];
        unsigned u0 = hs2[(long long)s0 * 64 + lane];
        unsigned u1 = hs2[(long long)s1 * 64 + lane];
        ax = fmaf(e0, bf_lo(u0), ax); ay = fmaf(e0, bf_hi(u0), ay);
        ax = fmaf(e1, bf_lo(u1), ax); ay = fmaf(e1, bf_hi(u1), ay);
    }
    if (j < c) {
        int s0 = eidx[offs + j];
        float e0 = dinv[s0];
        unsigned u0 = hs2[(long long)s0 * 64 + lane];
        ax = fmaf(e0, bf_lo(u0), ax); ay = fmaf(e0, bf_hi(u0), ay);
    }

    float2 bb = ((const float2*)b1)[lane];
    float2 ww = ((const float2*)W2)[lane];
    float r0 = fmaxf(fmaf(dw, ax, bb.x), 0.0f);
    float r1 = fmaxf(fmaf(dw, ay, bb.y), 0.0f);
    float v = r0 * ww.x + r1 * ww.y;
#pragma unroll
    for (int off = 32; off > 0; off >>= 1) v += __shfl_down(v, off);
    if (lane == 0) zs[w] = v * dw;
}

// ---------------- layer-2 aggregation + sigmoid epilogue (ILP-4) ----------------
__global__ void k_agg2_final(const int* __restrict__ eidx,
                             const int* __restrict__ excl,   // absolute
                             const int* __restrict__ cnt,
                             const float* __restrict__ zs,
                             const float* __restrict__ dinv,
                             const float* __restrict__ b2,
                             float* __restrict__ out) {
    int i = blockIdx.x * 256 + threadIdx.x;
    if (i >= NN) return;
    int offs = excl[i];
    int c = cnt[i];
    float v = zs[i];   // self-loop
    int j = 0;
    for (; j + 3 < c; j += 4) {
        int s0 = eidx[offs + j + 0];
        int s1 = eidx[offs + j + 1];
        int s2 = eidx[offs + j + 2];
        int s3 = eidx[offs + j + 3];
        v += zs[s0] + zs[s1] + zs[s2] + zs[s3];
    }
    for (; j < c; ++j) v += zs[eidx[offs + j]];
    float z = fmaf(dinv[i], v, b2[0]);
    out[i] = 1.0f / (1.0f + __expf(-z));
}

extern "C" void kernel_launch(void* const* d_in, const int* in_sizes, int n_in,
                              void* d_out, int out_size, void* d_ws, size_t ws_size,
                              hipStream_t stream) {
    const float* x  = (const float*)d_in[0];
    const int*   ei = (const int*)d_in[1];
    const float* W1 = (const float*)d_in[2];
    const float* b1 = (const float*)d_in[3];
    const float* W2 = (const float*)d_in[4];
    const float* b2 = (const float*)d_in[5];
    float* out = (float*)d_out;

    const int E = in_sizes[1] / 2;
    const int* src = ei;
    const int* dst = ei + E;

    // workspace layout (4-byte units; bucketArr 8B-aligned, hs 16B-aligned)
    int* wsi = (int*)d_ws;
    float* dinv       = (float*)wsi;                 // N
    int*   cnt        = wsi + NN;                    // N
    int*   excl       = cnt + NN;                    // N
    float* zs         = (float*)(excl + NN);         // N
    int*   bucketFill = (int*)(zs + NN);             // 256
    unsigned short* W1p = (unsigned short*)(bucketFill + 256);  // 32768 bf16 (= 16384 ints)
    int*   eidx       = (int*)(W1p + 32768);         // E
    int2*  bucketArr  = (int2*)(eidx + E);           // NB_BUCKET*BCAP pairs (~19.3 MB)
    unsigned short* hs = (unsigned short*)(bucketArr + (long long)NB_BUCKET * BCAP);  // N*128 bf16

    const int nb_nodes = (NN + 255) / 256;
    const int pa_nb = (E + PA_EDGES - 1) / PA_EDGES;

    hipMemsetAsync(bucketFill, 0, NB_BUCKET * sizeof(int), stream);

    k_prepW<<<128, 256, 0, stream>>>(W1, W1p);
    k_partA<<<pa_nb, 512, 0, stream>>>(src, dst, E, bucketFill, bucketArr);
    k_partB<<<NB_BUCKET, 512, 0, stream>>>(bucketFill, bucketArr, cnt, excl, dinv, eidx);
    k_gemm<<<GEMM_NB, 256, 0, stream>>>(x, W1p, hs);

    k_agg1l2<<<(NN * 64 + 255) / 256, 256, 0, stream>>>(eidx, excl, cnt,
                                                        (const unsigned*)hs, dinv, b1, W2, zs);

    k_agg2_final<<<nb_nodes, 256, 0, stream>>>(eidx, excl, cnt, zs, dinv, b2, out);
}